// Round 10
// baseline (221.462 us; speedup 1.0000x reference)
//
#include <hip/hip_runtime.h>
#include <hip/hip_fp16.h>

#define NN 100000
#define EE 1600000
#define CAP 64
#define NEG_SLOPE 0.2f
#define NEG_INF (-1e30f)

#define NPART 196      // ceil(100000 / 512)
#define PSHIFT 9       // 512 nodes per partition
#define CAPP 10240     // records per partition buffer (mean 8192, +22 sigma)
#define EPB 4096       // edges per pass-1 block
#define P1_BLOCKS 391  // ceil(EE / EPB)
#define PROJ_BLOCKS 512

struct alignas(8) H4 { __half2 a, b; };
struct alignas(16) H8 { __half2 a, b, c, d; };

using f16x8 = __attribute__((ext_vector_type(8))) _Float16;
using f32x4 = __attribute__((ext_vector_type(4))) float;

__device__ __forceinline__ float4 h4tof4lo(const H8& h) {
  const float2 a = __half22float2(h.a);
  const float2 b = __half22float2(h.b);
  return make_float4(a.x, a.y, b.x, b.y);
}
__device__ __forceinline__ float4 h4tof4hi(const H8& h) {
  const float2 a = __half22float2(h.c);
  const float2 b = __half22float2(h.d);
  return make_float4(a.x, a.y, b.x, b.y);
}

// ---------------- fused pass1-partition + dual-MFMA projection ----------------
// Blocks [0, P1_BLOCKS): partition edges by dst>>9. LDS histogram -> 196
// global atomics per block (76k total). Records per partition land
// contiguously -> no 64B-line write amplification (R8 lesson).
// Blocks [P1_BLOCKS, +PROJ_BLOCKS): MFMA projection (independent work),
// overlapped here because both paths are well-behaved streamers (R7 lesson:
// only atomic-storms interfere destructively).
__global__ __launch_bounds__(512) void part_proj(
    const int* __restrict__ ei, const float* __restrict__ eattr,
    int* __restrict__ partCount, uint2* __restrict__ partBuf,
    const float* __restrict__ x, const float* __restrict__ Wsrc,
    const float* __restrict__ bsrc, const float* __restrict__ Wdst,
    const float* __restrict__ bdst, __half* __restrict__ xsrc,
    __half* __restrict__ xdst) {
  __shared__ int hist[NPART];
  __shared__ int base[NPART];
  if (blockIdx.x < P1_BLOCKS) {
    // ---- partition path ----
    for (int i = threadIdx.x; i < NPART; i += 512) hist[i] = 0;
    __syncthreads();
    const int e0 = blockIdx.x * EPB;
    int p[8], rank[8];
    uint2 rec[8];
#pragma unroll
    for (int j = 0; j < 8; ++j) {
      const int e = e0 + j * 512 + threadIdx.x;
      if (e < EE) {
        const int dst = ei[EE + e];
        const int src = ei[e];
        const unsigned q = (unsigned)__float2uint_rn(eattr[e] * 32767.0f);
        p[j] = dst >> PSHIFT;
        rec[j].x = (unsigned)(dst & 511);
        rec[j].y = (q << 17) | (unsigned)src;
        rank[j] = atomicAdd(&hist[p[j]], 1);
      } else {
        p[j] = -1;
      }
    }
    __syncthreads();
    for (int i = threadIdx.x; i < NPART; i += 512)
      base[i] = atomicAdd(&partCount[i], hist[i]);
    __syncthreads();
#pragma unroll
    for (int j = 0; j < 8; ++j) {
      if (p[j] >= 0) {
        const int idx = base[p[j]] + rank[j];
        if (idx < CAPP) partBuf[(size_t)p[j] * CAPP + idx] = rec[j];
      }
    }
    return;
  }
  // ---- projection path (proven R6 MFMA kernel; xdst now fp16) ----
  const int bid = blockIdx.x - P1_BLOCKS;
  const int lane = threadIdx.x & 63;
  const int nc = threadIdx.x >> 6;  // col tile 0..7
  const int r = lane & 15;          // A-row / B-col / D-col
  const int kg = lane >> 4;         // k-group 0..3
  const int col = nc * 16 + r;

  f16x8 bs[4], bd[4];
#pragma unroll
  for (int kk = 0; kk < 4; ++kk) {
    const int kbase = kk * 32 + kg * 8;
#pragma unroll
    for (int j = 0; j < 8; ++j) {
      bs[kk][j] = (_Float16)Wsrc[(size_t)(kbase + j) * 128 + col];
      bd[kk][j] = (_Float16)Wdst[(size_t)(kbase + j) * 128 + col];
    }
  }
  const float bsv = bsrc[col];
  const float bdv = bdst[col];

  for (int t = bid; t < NN / 16; t += PROJ_BLOCKS) {
    const int r0 = t * 16;
    f16x8 a[4];
#pragma unroll
    for (int kk = 0; kk < 4; ++kk) {
      const float* xp = x + (size_t)(r0 + r) * 128 + kk * 32 + kg * 8;
      const float4 lo = *(const float4*)xp;
      const float4 hi = *(const float4*)(xp + 4);
      a[kk][0] = (_Float16)lo.x; a[kk][1] = (_Float16)lo.y;
      a[kk][2] = (_Float16)lo.z; a[kk][3] = (_Float16)lo.w;
      a[kk][4] = (_Float16)hi.x; a[kk][5] = (_Float16)hi.y;
      a[kk][6] = (_Float16)hi.z; a[kk][7] = (_Float16)hi.w;
    }
    f32x4 accs = {bsv, bsv, bsv, bsv};
    f32x4 accd = {bdv, bdv, bdv, bdv};
#pragma unroll
    for (int kk = 0; kk < 4; ++kk) {
      accs = __builtin_amdgcn_mfma_f32_16x16x32_f16(a[kk], bs[kk], accs, 0, 0, 0);
      accd = __builtin_amdgcn_mfma_f32_16x16x32_f16(a[kk], bd[kk], accd, 0, 0, 0);
    }
#pragma unroll
    for (int reg = 0; reg < 4; ++reg) {
      const size_t row = r0 + kg * 4 + reg;
      xsrc[row * 128 + col] = __float2half(accs[reg]);
      xdst[row * 128 + col] = __float2half(accd[reg]);
    }
  }
}

// ---------------- pass 2: bucket within each partition ----------------
// One block per partition (512 nodes); LDS counters; bucket stores hit a
// block-private 128KB region -> assembled in L2, written back once.
__global__ __launch_bounds__(512) void bucket2_kernel(
    const int* __restrict__ partCount, const uint2* __restrict__ partBuf,
    int* __restrict__ counts, unsigned* __restrict__ buckets) {
  __shared__ int cnt[512];
  const int pbase = blockIdx.x << PSHIFT;
  cnt[threadIdx.x] = 0;
  __syncthreads();
  int n = partCount[blockIdx.x];
  if (n > CAPP) n = CAPP;
  for (int i = threadIdx.x; i < n; i += 512) {
    const uint2 r = partBuf[(size_t)blockIdx.x * CAPP + i];
    const int pos = atomicAdd(&cnt[r.x], 1);
    if (pos < CAP) buckets[((size_t)(pbase + (int)r.x) << 6) + pos] = r.y;
  }
  __syncthreads();
  const int node = pbase + threadIdx.x;
  if (node < NN) counts[node] = cnt[threadIdx.x];
}

// ---------------- fused per-node kernel ----------------
// One wave per node; 4 groups x 16 lanes; lane sl owns channels 8sl..8sl+7.
// 4-deep gather pipeline; online softmax w/ defer-max; epilogue merges the 4
// group states then bias+LayerNorm+ELU+residual. xdst now fp16.
__global__ __launch_bounds__(256) void node_kernel(
    const __half* __restrict__ xsrc, const __half* __restrict__ xdst,
    const int* __restrict__ counts, const unsigned* __restrict__ buckets,
    const float* __restrict__ Wedge, const float* __restrict__ att,
    const float* __restrict__ bias, const float* __restrict__ gamma,
    const float* __restrict__ beta, const float* __restrict__ x,
    float* __restrict__ out) {
  const int lane = threadIdx.x & 63;
  const int node = blockIdx.x * 4 + (threadIdx.x >> 6);
  const int g = lane >> 4;
  const int sl = lane & 15;
  const int c0 = sl * 8;

  int deg = __builtin_nontemporal_load(&counts[node]);
  if (deg > CAP) deg = CAP;

  unsigned rec_l = 0;
  if (lane < deg) rec_l = __builtin_nontemporal_load(&buckets[node * CAP + lane]);

  const H8 xdh = ((const H8*)(xdst + (size_t)node * 128))[sl];
  const float4 xdA = h4tof4lo(xdh);
  const float4 xdB = h4tof4hi(xdh);
  const float4 weA = *(const float4*)(Wedge + c0);
  const float4 weB = *(const float4*)(Wedge + c0 + 4);
  const float4 atA = *(const float4*)(att + c0);
  const float4 atB = *(const float4*)(att + c0 + 4);

  float m = NEG_INF, den = 0.f;
  float4 accA = {0.f, 0.f, 0.f, 0.f};
  float4 accB = {0.f, 0.f, 0.f, 0.f};

#define PREFA(kk, V, EA, HV)                               \
  {                                                        \
    const int idx = (kk) + g;                              \
    V = idx < deg;                                         \
    const int ii = V ? idx : dlast;                        \
    const unsigned rec = __shfl((int)rec_l, ii);           \
    EA = (float)(rec >> 17) * (1.f / 32767.f);             \
    const int s = rec & 0x1FFFF;                           \
    HV = ((const H8*)(xsrc + (size_t)s * 128))[sl];        \
  }

#define COMPUTE(V, EA, HV)                                         \
  {                                                                \
    const float4 VA = h4tof4lo(HV);                                \
    const float4 VB = h4tof4hi(HV);                                \
    float t, lr, p = 0.f;                                          \
    t = VA.x + xdA.x + EA * weA.x; lr = fmaxf(t, NEG_SLOPE * t); p = fmaf(lr, atA.x, p); \
    t = VA.y + xdA.y + EA * weA.y; lr = fmaxf(t, NEG_SLOPE * t); p = fmaf(lr, atA.y, p); \
    t = VA.z + xdA.z + EA * weA.z; lr = fmaxf(t, NEG_SLOPE * t); p = fmaf(lr, atA.z, p); \
    t = VA.w + xdA.w + EA * weA.w; lr = fmaxf(t, NEG_SLOPE * t); p = fmaf(lr, atA.w, p); \
    t = VB.x + xdB.x + EA * weB.x; lr = fmaxf(t, NEG_SLOPE * t); p = fmaf(lr, atB.x, p); \
    t = VB.y + xdB.y + EA * weB.y; lr = fmaxf(t, NEG_SLOPE * t); p = fmaf(lr, atB.y, p); \
    t = VB.z + xdB.z + EA * weB.z; lr = fmaxf(t, NEG_SLOPE * t); p = fmaf(lr, atB.z, p); \
    t = VB.w + xdB.w + EA * weB.w; lr = fmaxf(t, NEG_SLOPE * t); p = fmaf(lr, atB.w, p); \
    p += __shfl_xor(p, 1);                                         \
    p = V ? p : NEG_INF;                                           \
    if (p <= m) { /* common: max unchanged */                      \
      float ex = V ? __expf(p - m) : 0.f;                          \
      den += ex;                                                   \
      accA.x = fmaf(ex, VA.x, accA.x); accA.y = fmaf(ex, VA.y, accA.y); \
      accA.z = fmaf(ex, VA.z, accA.z); accA.w = fmaf(ex, VA.w, accA.w); \
      accB.x = fmaf(ex, VB.x, accB.x); accB.y = fmaf(ex, VB.y, accB.y); \
      accB.z = fmaf(ex, VB.z, accB.z); accB.w = fmaf(ex, VB.w, accB.w); \
    } else { /* new max: ex = 1 */                                 \
      const float sc = __expf(m - p);                              \
      den = fmaf(den, sc, 1.f);                                    \
      accA.x = fmaf(accA.x, sc, VA.x); accA.y = fmaf(accA.y, sc, VA.y); \
      accA.z = fmaf(accA.z, sc, VA.z); accA.w = fmaf(accA.w, sc, VA.w); \
      accB.x = fmaf(accB.x, sc, VB.x); accB.y = fmaf(accB.y, sc, VB.y); \
      accB.z = fmaf(accB.z, sc, VB.z); accB.w = fmaf(accB.w, sc, VB.w); \
      m = p;                                                       \
    }                                                              \
  }

  if (deg > 0) {
    const int dlast = deg - 1;
    bool v0, v1, v2, v3;
    float e0, e1, e2, e3;
    H8 h0, h1, h2, h3;
    PREFA(0, v0, e0, h0);
    PREFA(4, v1, e1, h1);
    PREFA(8, v2, e2, h2);
    PREFA(12, v3, e3, h3);
    for (int k = 0; k < deg; k += 4) {
      COMPUTE(v0, e0, h0);
      v0 = v1; e0 = e1; h0 = h1;
      v1 = v2; e1 = e2; h1 = h2;
      v2 = v3; e2 = e3; h2 = h3;
      PREFA(k + 16, v3, e3, h3);
    }
  }
#undef PREFA
#undef COMPUTE

  // ---- merge the 4 group states (lanes l, l^16, l^32, l^48) ----
#pragma unroll
  for (int d = 16; d < 64; d <<= 1) {
    const float mo = __shfl_xor(m, d);
    const float dno = __shfl_xor(den, d);
    const float oAx = __shfl_xor(accA.x, d), oAy = __shfl_xor(accA.y, d);
    const float oAz = __shfl_xor(accA.z, d), oAw = __shfl_xor(accA.w, d);
    const float oBx = __shfl_xor(accB.x, d), oBy = __shfl_xor(accB.y, d);
    const float oBz = __shfl_xor(accB.z, d), oBw = __shfl_xor(accB.w, d);
    const float mn = fmaxf(m, mo);
    const float sa = __expf(m - mn);
    const float sb = __expf(mo - mn);
    den = den * sa + dno * sb;
    accA.x = accA.x * sa + oAx * sb; accA.y = accA.y * sa + oAy * sb;
    accA.z = accA.z * sa + oAz * sb; accA.w = accA.w * sa + oAw * sb;
    accB.x = accB.x * sa + oBx * sb; accB.y = accB.y * sa + oBy * sb;
    accB.z = accB.z * sa + oBz * sb; accB.w = accB.w * sa + oBw * sb;
    m = mn;
  }

  const float inv = den > 0.f ? 1.f / den : 0.f;
  float o[8];
  const float4 biA = *(const float4*)(bias + c0);
  const float4 biB = *(const float4*)(bias + c0 + 4);
  o[0] = accA.x * inv + biA.x; o[1] = accA.y * inv + biA.y;
  o[2] = accA.z * inv + biA.z; o[3] = accA.w * inv + biA.w;
  o[4] = accB.x * inv + biB.x; o[5] = accB.y * inv + biB.y;
  o[6] = accB.z * inv + biB.z; o[7] = accB.w * inv + biB.w;

  // LayerNorm over 128 channels: per-lane partial over its 8, reduce over sl
  float s = 0.f;
#pragma unroll
  for (int j = 0; j < 8; ++j) s += o[j];
#pragma unroll
  for (int d = 1; d < 16; d <<= 1) s += __shfl_xor(s, d);
  const float mu = s * (1.f / 128.f);
  float q = 0.f;
#pragma unroll
  for (int j = 0; j < 8; ++j) {
    o[j] -= mu;
    q += o[j] * o[j];
  }
#pragma unroll
  for (int d = 1; d < 16; d <<= 1) q += __shfl_xor(q, d);
  const float r = rsqrtf(q * (1.f / 128.f) + 1e-5f);

  if (g == 0) {
    const float4 gaA = *(const float4*)(gamma + c0);
    const float4 gaB = *(const float4*)(gamma + c0 + 4);
    const float4 beA = *(const float4*)(beta + c0);
    const float4 beB = *(const float4*)(beta + c0 + 4);
    const float4 xrA = *(const float4*)(x + (size_t)node * 128 + c0);
    const float4 xrB = *(const float4*)(x + (size_t)node * 128 + c0 + 4);
    float ga[8] = {gaA.x, gaA.y, gaA.z, gaA.w, gaB.x, gaB.y, gaB.z, gaB.w};
    float be[8] = {beA.x, beA.y, beA.z, beA.w, beB.x, beB.y, beB.z, beB.w};
    float xr[8] = {xrA.x, xrA.y, xrA.z, xrA.w, xrB.x, xrB.y, xrB.z, xrB.w};
    float y[8];
#pragma unroll
    for (int j = 0; j < 8; ++j) {
      float v = o[j] * r * ga[j] + be[j];
      v = v > 0.f ? v : expm1f(v);
      y[j] = v + xr[j];
    }
    float4 oA = {y[0], y[1], y[2], y[3]};
    float4 oB = {y[4], y[5], y[6], y[7]};
    *(float4*)(out + (size_t)node * 128 + c0) = oA;
    *(float4*)(out + (size_t)node * 128 + c0 + 4) = oB;
  }
}

extern "C" void kernel_launch(void* const* d_in, const int* in_sizes, int n_in,
                              void* d_out, int out_size, void* d_ws, size_t ws_size,
                              hipStream_t stream) {
  const float* x = (const float*)d_in[0];
  const int* ei = (const int*)d_in[1];
  const float* eattr = (const float*)d_in[2];
  const float* Wsrc = (const float*)d_in[3];
  const float* bsrc = (const float*)d_in[4];
  const float* Wdst = (const float*)d_in[5];
  const float* bdst = (const float*)d_in[6];
  const float* Wedge = (const float*)d_in[7];
  const float* att = (const float*)d_in[8];
  const float* bias = (const float*)d_in[9];
  const float* gamma = (const float*)d_in[10];
  const float* beta = (const float*)d_in[11];
  float* out = (float*)d_out;

  // ws: xsrc fp16 25.6MB | xdst fp16 25.6MB | counts 0.4MB | buckets 25.6MB |
  //     partCount 1KB | partBuf uint2 16MB   (~94MB total)
  __half* xsrc = (__half*)d_ws;
  __half* xdst = xsrc + (size_t)NN * 128;
  int* counts = (int*)(xdst + (size_t)NN * 128);
  unsigned* buckets = (unsigned*)(counts + NN);
  int* partCount = (int*)(buckets + (size_t)NN * CAP);
  uint2* partBuf = (uint2*)(partCount + 256);

  hipMemsetAsync(partCount, 0, NPART * sizeof(int), stream);
  part_proj<<<dim3(P1_BLOCKS + PROJ_BLOCKS), dim3(512), 0, stream>>>(
      ei, eattr, partCount, partBuf, x, Wsrc, bsrc, Wdst, bdst, xsrc, xdst);
  bucket2_kernel<<<dim3(NPART), dim3(512), 0, stream>>>(partCount, partBuf, counts, buckets);
  node_kernel<<<dim3(NN / 4), dim3(256), 0, stream>>>(xsrc, xdst, counts, buckets,
                                                      Wedge, att, bias, gamma,
                                                      beta, x, out);
}

// Round 11
// 220.144 us; speedup vs baseline: 1.0060x; 1.0060x over previous
//
#include <hip/hip_runtime.h>
#include <hip/hip_fp16.h>

#define NN 100000
#define EE 1600000
#define CAP 64
#define NEG_SLOPE 0.2f
#define NEG_INF (-1e30f)

#define NPART 196      // ceil(100000 / 512)
#define PSHIFT 9       // 512 nodes per partition
#define CAPP 10240     // records per partition buffer (mean 8163, +23 sigma)
#define EPB 4096       // edges per pass-1 block
#define P1_BLOCKS 391  // ceil(EE / EPB)
#define PROJ_BLOCKS 1024

struct alignas(8) H4 { __half2 a, b; };
struct alignas(16) H8 { __half2 a, b, c, d; };

using f16x8 = __attribute__((ext_vector_type(8))) _Float16;
using f32x4 = __attribute__((ext_vector_type(4))) float;

__device__ __forceinline__ float4 h4tof4lo(const H8& h) {
  const float2 a = __half22float2(h.a);
  const float2 b = __half22float2(h.b);
  return make_float4(a.x, a.y, b.x, b.y);
}
__device__ __forceinline__ float4 h4tof4hi(const H8& h) {
  const float2 a = __half22float2(h.c);
  const float2 b = __half22float2(h.d);
  return make_float4(a.x, a.y, b.x, b.y);
}

// ---------------- pass 1: partition edges by dst>>9 ----------------
// LDS histogram -> 196 global atomics per block (76k total). Records per
// partition land contiguously -> no 64B-line write amplification (R8 lesson).
// Runs STANDALONE: co-scheduling it with the proj streamer regressed (R10).
__global__ __launch_bounds__(512) void partition_kernel(
    const int* __restrict__ ei, const float* __restrict__ eattr,
    int* __restrict__ partCount, uint2* __restrict__ partBuf) {
  __shared__ int hist[NPART];
  __shared__ int base[NPART];
  for (int i = threadIdx.x; i < NPART; i += 512) hist[i] = 0;
  __syncthreads();
  const int e0 = blockIdx.x * EPB;
  int p[8], rank[8];
  uint2 rec[8];
#pragma unroll
  for (int j = 0; j < 8; ++j) {
    const int e = e0 + j * 512 + threadIdx.x;
    if (e < EE) {
      const int dst = ei[EE + e];
      const int src = ei[e];
      const unsigned q = (unsigned)__float2uint_rn(eattr[e] * 32767.0f);
      p[j] = dst >> PSHIFT;
      rec[j].x = (unsigned)(dst & 511);
      rec[j].y = (q << 17) | (unsigned)src;
      rank[j] = atomicAdd(&hist[p[j]], 1);
    } else {
      p[j] = -1;
    }
  }
  __syncthreads();
  for (int i = threadIdx.x; i < NPART; i += 512)
    base[i] = atomicAdd(&partCount[i], hist[i]);
  __syncthreads();
#pragma unroll
  for (int j = 0; j < 8; ++j) {
    if (p[j] >= 0) {
      const int idx = base[p[j]] + rank[j];
      if (idx < CAPP) partBuf[(size_t)p[j] * CAPP + idx] = rec[j];
    }
  }
}

// ---------------- pass 2: bucket within each partition ----------------
// One block per partition (512 nodes); LDS counters; bucket stores hit a
// block-private 128KB region -> assembled in L2, written back once.
__global__ __launch_bounds__(512) void bucket2_kernel(
    const int* __restrict__ partCount, const uint2* __restrict__ partBuf,
    int* __restrict__ counts, unsigned* __restrict__ buckets) {
  __shared__ int cnt[512];
  const int pbase = blockIdx.x << PSHIFT;
  cnt[threadIdx.x] = 0;
  __syncthreads();
  int n = partCount[blockIdx.x];
  if (n > CAPP) n = CAPP;
  for (int i = threadIdx.x; i < n; i += 512) {
    const uint2 r = partBuf[(size_t)blockIdx.x * CAPP + i];
    const int pos = atomicAdd(&cnt[r.x], 1);
    if (pos < CAP) buckets[((size_t)(pbase + (int)r.x) << 6) + pos] = r.y;
  }
  __syncthreads();
  const int node = pbase + threadIdx.x;
  if (node < NN) counts[node] = cnt[threadIdx.x];
}

// ---------------- dual projection via MFMA (proven R6 kernel, fp16 xdst) ----
__global__ __launch_bounds__(512) void proj_mfma(const float* __restrict__ x,
                                                 const float* __restrict__ Wsrc,
                                                 const float* __restrict__ bsrc,
                                                 const float* __restrict__ Wdst,
                                                 const float* __restrict__ bdst,
                                                 __half* __restrict__ xsrc,
                                                 __half* __restrict__ xdst) {
  const int lane = threadIdx.x & 63;
  const int nc = threadIdx.x >> 6;  // col tile 0..7
  const int r = lane & 15;          // A-row / B-col / D-col
  const int kg = lane >> 4;         // k-group 0..3
  const int col = nc * 16 + r;

  f16x8 bs[4], bd[4];
#pragma unroll
  for (int kk = 0; kk < 4; ++kk) {
    const int kbase = kk * 32 + kg * 8;
#pragma unroll
    for (int j = 0; j < 8; ++j) {
      bs[kk][j] = (_Float16)Wsrc[(size_t)(kbase + j) * 128 + col];
      bd[kk][j] = (_Float16)Wdst[(size_t)(kbase + j) * 128 + col];
    }
  }
  const float bsv = bsrc[col];
  const float bdv = bdst[col];

  for (int t = blockIdx.x; t < NN / 16; t += PROJ_BLOCKS) {
    const int r0 = t * 16;
    f16x8 a[4];
#pragma unroll
    for (int kk = 0; kk < 4; ++kk) {
      const float* xp = x + (size_t)(r0 + r) * 128 + kk * 32 + kg * 8;
      const float4 lo = *(const float4*)xp;
      const float4 hi = *(const float4*)(xp + 4);
      a[kk][0] = (_Float16)lo.x; a[kk][1] = (_Float16)lo.y;
      a[kk][2] = (_Float16)lo.z; a[kk][3] = (_Float16)lo.w;
      a[kk][4] = (_Float16)hi.x; a[kk][5] = (_Float16)hi.y;
      a[kk][6] = (_Float16)hi.z; a[kk][7] = (_Float16)hi.w;
    }
    f32x4 accs = {bsv, bsv, bsv, bsv};
    f32x4 accd = {bdv, bdv, bdv, bdv};
#pragma unroll
    for (int kk = 0; kk < 4; ++kk) {
      accs = __builtin_amdgcn_mfma_f32_16x16x32_f16(a[kk], bs[kk], accs, 0, 0, 0);
      accd = __builtin_amdgcn_mfma_f32_16x16x32_f16(a[kk], bd[kk], accd, 0, 0, 0);
    }
#pragma unroll
    for (int reg = 0; reg < 4; ++reg) {
      const size_t row = r0 + kg * 4 + reg;
      xsrc[row * 128 + col] = __float2half(accs[reg]);
      xdst[row * 128 + col] = __float2half(accd[reg]);
    }
  }
}

// ---------------- fused per-node kernel (unchanged from R10) ----------------
__global__ __launch_bounds__(256) void node_kernel(
    const __half* __restrict__ xsrc, const __half* __restrict__ xdst,
    const int* __restrict__ counts, const unsigned* __restrict__ buckets,
    const float* __restrict__ Wedge, const float* __restrict__ att,
    const float* __restrict__ bias, const float* __restrict__ gamma,
    const float* __restrict__ beta, const float* __restrict__ x,
    float* __restrict__ out) {
  const int lane = threadIdx.x & 63;
  const int node = blockIdx.x * 4 + (threadIdx.x >> 6);
  const int g = lane >> 4;
  const int sl = lane & 15;
  const int c0 = sl * 8;

  int deg = __builtin_nontemporal_load(&counts[node]);
  if (deg > CAP) deg = CAP;

  unsigned rec_l = 0;
  if (lane < deg) rec_l = __builtin_nontemporal_load(&buckets[node * CAP + lane]);

  const H8 xdh = ((const H8*)(xdst + (size_t)node * 128))[sl];
  const float4 xdA = h4tof4lo(xdh);
  const float4 xdB = h4tof4hi(xdh);
  const float4 weA = *(const float4*)(Wedge + c0);
  const float4 weB = *(const float4*)(Wedge + c0 + 4);
  const float4 atA = *(const float4*)(att + c0);
  const float4 atB = *(const float4*)(att + c0 + 4);

  float m = NEG_INF, den = 0.f;
  float4 accA = {0.f, 0.f, 0.f, 0.f};
  float4 accB = {0.f, 0.f, 0.f, 0.f};

#define PREFA(kk, V, EA, HV)                               \
  {                                                        \
    const int idx = (kk) + g;                              \
    V = idx < deg;                                         \
    const int ii = V ? idx : dlast;                        \
    const unsigned rec = __shfl((int)rec_l, ii);           \
    EA = (float)(rec >> 17) * (1.f / 32767.f);             \
    const int s = rec & 0x1FFFF;                           \
    HV = ((const H8*)(xsrc + (size_t)s * 128))[sl];        \
  }

#define COMPUTE(V, EA, HV)                                         \
  {                                                                \
    const float4 VA = h4tof4lo(HV);                                \
    const float4 VB = h4tof4hi(HV);                                \
    float t, lr, p = 0.f;                                          \
    t = VA.x + xdA.x + EA * weA.x; lr = fmaxf(t, NEG_SLOPE * t); p = fmaf(lr, atA.x, p); \
    t = VA.y + xdA.y + EA * weA.y; lr = fmaxf(t, NEG_SLOPE * t); p = fmaf(lr, atA.y, p); \
    t = VA.z + xdA.z + EA * weA.z; lr = fmaxf(t, NEG_SLOPE * t); p = fmaf(lr, atA.z, p); \
    t = VA.w + xdA.w + EA * weA.w; lr = fmaxf(t, NEG_SLOPE * t); p = fmaf(lr, atA.w, p); \
    t = VB.x + xdB.x + EA * weB.x; lr = fmaxf(t, NEG_SLOPE * t); p = fmaf(lr, atB.x, p); \
    t = VB.y + xdB.y + EA * weB.y; lr = fmaxf(t, NEG_SLOPE * t); p = fmaf(lr, atB.y, p); \
    t = VB.z + xdB.z + EA * weB.z; lr = fmaxf(t, NEG_SLOPE * t); p = fmaf(lr, atB.z, p); \
    t = VB.w + xdB.w + EA * weB.w; lr = fmaxf(t, NEG_SLOPE * t); p = fmaf(lr, atB.w, p); \
    p += __shfl_xor(p, 1);                                         \
    p = V ? p : NEG_INF;                                           \
    if (p <= m) { /* common: max unchanged */                      \
      float ex = V ? __expf(p - m) : 0.f;                          \
      den += ex;                                                   \
      accA.x = fmaf(ex, VA.x, accA.x); accA.y = fmaf(ex, VA.y, accA.y); \
      accA.z = fmaf(ex, VA.z, accA.z); accA.w = fmaf(ex, VA.w, accA.w); \
      accB.x = fmaf(ex, VB.x, accB.x); accB.y = fmaf(ex, VB.y, accB.y); \
      accB.z = fmaf(ex, VB.z, accB.z); accB.w = fmaf(ex, VB.w, accB.w); \
    } else { /* new max: ex = 1 */                                 \
      const float sc = __expf(m - p);                              \
      den = fmaf(den, sc, 1.f);                                    \
      accA.x = fmaf(accA.x, sc, VA.x); accA.y = fmaf(accA.y, sc, VA.y); \
      accA.z = fmaf(accA.z, sc, VA.z); accA.w = fmaf(accA.w, sc, VA.w); \
      accB.x = fmaf(accB.x, sc, VB.x); accB.y = fmaf(accB.y, sc, VB.y); \
      accB.z = fmaf(accB.z, sc, VB.z); accB.w = fmaf(accB.w, sc, VB.w); \
      m = p;                                                       \
    }                                                              \
  }

  if (deg > 0) {
    const int dlast = deg - 1;
    bool v0, v1, v2, v3;
    float e0, e1, e2, e3;
    H8 h0, h1, h2, h3;
    PREFA(0, v0, e0, h0);
    PREFA(4, v1, e1, h1);
    PREFA(8, v2, e2, h2);
    PREFA(12, v3, e3, h3);
    for (int k = 0; k < deg; k += 4) {
      COMPUTE(v0, e0, h0);
      v0 = v1; e0 = e1; h0 = h1;
      v1 = v2; e1 = e2; h1 = h2;
      v2 = v3; e2 = e3; h2 = h3;
      PREFA(k + 16, v3, e3, h3);
    }
  }
#undef PREFA
#undef COMPUTE

  // ---- merge the 4 group states (lanes l, l^16, l^32, l^48) ----
#pragma unroll
  for (int d = 16; d < 64; d <<= 1) {
    const float mo = __shfl_xor(m, d);
    const float dno = __shfl_xor(den, d);
    const float oAx = __shfl_xor(accA.x, d), oAy = __shfl_xor(accA.y, d);
    const float oAz = __shfl_xor(accA.z, d), oAw = __shfl_xor(accA.w, d);
    const float oBx = __shfl_xor(accB.x, d), oBy = __shfl_xor(accB.y, d);
    const float oBz = __shfl_xor(accB.z, d), oBw = __shfl_xor(accB.w, d);
    const float mn = fmaxf(m, mo);
    const float sa = __expf(m - mn);
    const float sb = __expf(mo - mn);
    den = den * sa + dno * sb;
    accA.x = accA.x * sa + oAx * sb; accA.y = accA.y * sa + oAy * sb;
    accA.z = accA.z * sa + oAz * sb; accA.w = accA.w * sa + oAw * sb;
    accB.x = accB.x * sa + oBx * sb; accB.y = accB.y * sa + oBy * sb;
    accB.z = accB.z * sa + oBz * sb; accB.w = accB.w * sa + oBw * sb;
    m = mn;
  }

  const float inv = den > 0.f ? 1.f / den : 0.f;
  float o[8];
  const float4 biA = *(const float4*)(bias + c0);
  const float4 biB = *(const float4*)(bias + c0 + 4);
  o[0] = accA.x * inv + biA.x; o[1] = accA.y * inv + biA.y;
  o[2] = accA.z * inv + biA.z; o[3] = accA.w * inv + biA.w;
  o[4] = accB.x * inv + biB.x; o[5] = accB.y * inv + biB.y;
  o[6] = accB.z * inv + biB.z; o[7] = accB.w * inv + biB.w;

  // LayerNorm over 128 channels: per-lane partial over its 8, reduce over sl
  float s = 0.f;
#pragma unroll
  for (int j = 0; j < 8; ++j) s += o[j];
#pragma unroll
  for (int d = 1; d < 16; d <<= 1) s += __shfl_xor(s, d);
  const float mu = s * (1.f / 128.f);
  float q = 0.f;
#pragma unroll
  for (int j = 0; j < 8; ++j) {
    o[j] -= mu;
    q += o[j] * o[j];
  }
#pragma unroll
  for (int d = 1; d < 16; d <<= 1) q += __shfl_xor(q, d);
  const float r = rsqrtf(q * (1.f / 128.f) + 1e-5f);

  if (g == 0) {
    const float4 gaA = *(const float4*)(gamma + c0);
    const float4 gaB = *(const float4*)(gamma + c0 + 4);
    const float4 beA = *(const float4*)(beta + c0);
    const float4 beB = *(const float4*)(beta + c0 + 4);
    const float4 xrA = *(const float4*)(x + (size_t)node * 128 + c0);
    const float4 xrB = *(const float4*)(x + (size_t)node * 128 + c0 + 4);
    float ga[8] = {gaA.x, gaA.y, gaA.z, gaA.w, gaB.x, gaB.y, gaB.z, gaB.w};
    float be[8] = {beA.x, beA.y, beA.z, beA.w, beB.x, beB.y, beB.z, beB.w};
    float xr[8] = {xrA.x, xrA.y, xrA.z, xrA.w, xrB.x, xrB.y, xrB.z, xrB.w};
    float y[8];
#pragma unroll
    for (int j = 0; j < 8; ++j) {
      float v = o[j] * r * ga[j] + be[j];
      v = v > 0.f ? v : expm1f(v);
      y[j] = v + xr[j];
    }
    float4 oA = {y[0], y[1], y[2], y[3]};
    float4 oB = {y[4], y[5], y[6], y[7]};
    *(float4*)(out + (size_t)node * 128 + c0) = oA;
    *(float4*)(out + (size_t)node * 128 + c0 + 4) = oB;
  }
}

extern "C" void kernel_launch(void* const* d_in, const int* in_sizes, int n_in,
                              void* d_out, int out_size, void* d_ws, size_t ws_size,
                              hipStream_t stream) {
  const float* x = (const float*)d_in[0];
  const int* ei = (const int*)d_in[1];
  const float* eattr = (const float*)d_in[2];
  const float* Wsrc = (const float*)d_in[3];
  const float* bsrc = (const float*)d_in[4];
  const float* Wdst = (const float*)d_in[5];
  const float* bdst = (const float*)d_in[6];
  const float* Wedge = (const float*)d_in[7];
  const float* att = (const float*)d_in[8];
  const float* bias = (const float*)d_in[9];
  const float* gamma = (const float*)d_in[10];
  const float* beta = (const float*)d_in[11];
  float* out = (float*)d_out;

  // ws: xsrc fp16 25.6MB | xdst fp16 25.6MB | counts 0.4MB | buckets 25.6MB |
  //     partCount 1KB | partBuf uint2 16MB   (~94MB total)
  __half* xsrc = (__half*)d_ws;
  __half* xdst = xsrc + (size_t)NN * 128;
  int* counts = (int*)(xdst + (size_t)NN * 128);
  unsigned* buckets = (unsigned*)(counts + NN);
  int* partCount = (int*)(buckets + (size_t)NN * CAP);
  uint2* partBuf = (uint2*)(partCount + 256);

  hipMemsetAsync(partCount, 0, NPART * sizeof(int), stream);
  partition_kernel<<<dim3(P1_BLOCKS), dim3(512), 0, stream>>>(ei, eattr, partCount, partBuf);
  bucket2_kernel<<<dim3(NPART), dim3(512), 0, stream>>>(partCount, partBuf, counts, buckets);
  proj_mfma<<<dim3(PROJ_BLOCKS), dim3(512), 0, stream>>>(x, Wsrc, bsrc, Wdst, bdst, xsrc, xdst);
  node_kernel<<<dim3(NN / 4), dim3(256), 0, stream>>>(xsrc, xdst, counts, buckets,
                                                      Wedge, att, bias, gamma,
                                                      beta, x, out);
}

// Round 12
// 204.576 us; speedup vs baseline: 1.0825x; 1.0761x over previous
//
#include <hip/hip_runtime.h>
#include <hip/hip_fp16.h>

#define NN 100000
#define EE 1600000
#define CAP 64
#define NEG_SLOPE 0.2f
#define NEG_INF (-1e30f)

#define NPART 196      // ceil(100000 / 512)
#define PSHIFT 9       // 512 nodes per partition
#define CAPP 10240     // records per partition buffer (mean 8163, +23 sigma)
#define EPB 4096       // edges per pass-1 block
#define P1_BLOCKS 391  // ceil(EE / EPB)
#define PROJ_BLOCKS 512

struct alignas(8) H4 { __half2 a, b; };
struct alignas(16) H8 { __half2 a, b, c, d; };

using f16x8 = __attribute__((ext_vector_type(8))) _Float16;
using f32x4 = __attribute__((ext_vector_type(4))) float;

__device__ __forceinline__ float4 h4tof4lo(const H8& h) {
  const float2 a = __half22float2(h.a);
  const float2 b = __half22float2(h.b);
  return make_float4(a.x, a.y, b.x, b.y);
}
__device__ __forceinline__ float4 h4tof4hi(const H8& h) {
  const float2 a = __half22float2(h.c);
  const float2 b = __half22float2(h.d);
  return make_float4(a.x, a.y, b.x, b.y);
}

// ---------------- pass 1: partition edges by dst>>9 ----------------
// LDS histogram -> 196 global atomics per block (76k total). Records per
// partition land contiguously -> no 64B-line write amplification (R8 lesson).
// Runs STANDALONE: co-scheduling it with the proj streamer regressed (R10).
__global__ __launch_bounds__(512) void partition_kernel(
    const int* __restrict__ ei, const float* __restrict__ eattr,
    int* __restrict__ partCount, uint2* __restrict__ partBuf) {
  __shared__ int hist[NPART];
  __shared__ int base[NPART];
  for (int i = threadIdx.x; i < NPART; i += 512) hist[i] = 0;
  __syncthreads();
  const int e0 = blockIdx.x * EPB;
  int p[8], rank[8];
  uint2 rec[8];
#pragma unroll
  for (int j = 0; j < 8; ++j) {
    const int e = e0 + j * 512 + threadIdx.x;
    if (e < EE) {
      const int dst = ei[EE + e];
      const int src = ei[e];
      const unsigned q = (unsigned)__float2uint_rn(eattr[e] * 32767.0f);
      p[j] = dst >> PSHIFT;
      rec[j].x = (unsigned)(dst & 511);
      rec[j].y = (q << 17) | (unsigned)src;
      rank[j] = atomicAdd(&hist[p[j]], 1);
    } else {
      p[j] = -1;
    }
  }
  __syncthreads();
  for (int i = threadIdx.x; i < NPART; i += 512)
    base[i] = atomicAdd(&partCount[i], hist[i]);
  __syncthreads();
#pragma unroll
  for (int j = 0; j < 8; ++j) {
    if (p[j] >= 0) {
      const int idx = base[p[j]] + rank[j];
      if (idx < CAPP) partBuf[(size_t)p[j] * CAPP + idx] = rec[j];
    }
  }
}

// ---------------- fused pass2-bucket + dual-MFMA projection ----------------
// bucket2 alone uses 196 blocks (~38% of CUs) and leaves the rest idle; proj
// is independent of it (needs only x/W). Block-split fusion fills the idle
// CUs. Safe per R7/R10 lessons: bucket2 has LDS-only atomics + streaming
// reads/writes — no global-atomic storm to poison the proj path.
__global__ __launch_bounds__(512) void bucket_proj(
    const int* __restrict__ partCount, const uint2* __restrict__ partBuf,
    int* __restrict__ counts, unsigned* __restrict__ buckets,
    const float* __restrict__ x, const float* __restrict__ Wsrc,
    const float* __restrict__ bsrc, const float* __restrict__ Wdst,
    const float* __restrict__ bdst, __half* __restrict__ xsrc,
    __half* __restrict__ xdst) {
  __shared__ int cnt[512];
  if (blockIdx.x < NPART) {
    // ---- bucket path: one block per partition (512 nodes) ----
    const int pbase = blockIdx.x << PSHIFT;
    cnt[threadIdx.x] = 0;
    __syncthreads();
    int n = partCount[blockIdx.x];
    if (n > CAPP) n = CAPP;
    for (int i = threadIdx.x; i < n; i += 512) {
      const uint2 r = partBuf[(size_t)blockIdx.x * CAPP + i];
      const int pos = atomicAdd(&cnt[r.x], 1);
      if (pos < CAP) buckets[((size_t)(pbase + (int)r.x) << 6) + pos] = r.y;
    }
    __syncthreads();
    const int node = pbase + threadIdx.x;
    if (node < NN) counts[node] = cnt[threadIdx.x];
    return;
  }
  // ---- projection path (proven R6 MFMA kernel; fp16 outputs) ----
  const int bid = blockIdx.x - NPART;
  const int lane = threadIdx.x & 63;
  const int nc = threadIdx.x >> 6;  // col tile 0..7
  const int r = lane & 15;          // A-row / B-col / D-col
  const int kg = lane >> 4;         // k-group 0..3
  const int col = nc * 16 + r;

  f16x8 bs[4], bd[4];
#pragma unroll
  for (int kk = 0; kk < 4; ++kk) {
    const int kbase = kk * 32 + kg * 8;
#pragma unroll
    for (int j = 0; j < 8; ++j) {
      bs[kk][j] = (_Float16)Wsrc[(size_t)(kbase + j) * 128 + col];
      bd[kk][j] = (_Float16)Wdst[(size_t)(kbase + j) * 128 + col];
    }
  }
  const float bsv = bsrc[col];
  const float bdv = bdst[col];

  for (int t = bid; t < NN / 16; t += PROJ_BLOCKS) {
    const int r0 = t * 16;
    f16x8 a[4];
#pragma unroll
    for (int kk = 0; kk < 4; ++kk) {
      const float* xp = x + (size_t)(r0 + r) * 128 + kk * 32 + kg * 8;
      const float4 lo = *(const float4*)xp;
      const float4 hi = *(const float4*)(xp + 4);
      a[kk][0] = (_Float16)lo.x; a[kk][1] = (_Float16)lo.y;
      a[kk][2] = (_Float16)lo.z; a[kk][3] = (_Float16)lo.w;
      a[kk][4] = (_Float16)hi.x; a[kk][5] = (_Float16)hi.y;
      a[kk][6] = (_Float16)hi.z; a[kk][7] = (_Float16)hi.w;
    }
    f32x4 accs = {bsv, bsv, bsv, bsv};
    f32x4 accd = {bdv, bdv, bdv, bdv};
#pragma unroll
    for (int kk = 0; kk < 4; ++kk) {
      accs = __builtin_amdgcn_mfma_f32_16x16x32_f16(a[kk], bs[kk], accs, 0, 0, 0);
      accd = __builtin_amdgcn_mfma_f32_16x16x32_f16(a[kk], bd[kk], accd, 0, 0, 0);
    }
#pragma unroll
    for (int reg = 0; reg < 4; ++reg) {
      const size_t row = r0 + kg * 4 + reg;
      xsrc[row * 128 + col] = __float2half(accs[reg]);
      xdst[row * 128 + col] = __float2half(accd[reg]);
    }
  }
}

// ---------------- fused per-node kernel (unchanged from R10/R11) ----------------
__global__ __launch_bounds__(256) void node_kernel(
    const __half* __restrict__ xsrc, const __half* __restrict__ xdst,
    const int* __restrict__ counts, const unsigned* __restrict__ buckets,
    const float* __restrict__ Wedge, const float* __restrict__ att,
    const float* __restrict__ bias, const float* __restrict__ gamma,
    const float* __restrict__ beta, const float* __restrict__ x,
    float* __restrict__ out) {
  const int lane = threadIdx.x & 63;
  const int node = blockIdx.x * 4 + (threadIdx.x >> 6);
  const int g = lane >> 4;
  const int sl = lane & 15;
  const int c0 = sl * 8;

  int deg = __builtin_nontemporal_load(&counts[node]);
  if (deg > CAP) deg = CAP;

  unsigned rec_l = 0;
  if (lane < deg) rec_l = __builtin_nontemporal_load(&buckets[node * CAP + lane]);

  const H8 xdh = ((const H8*)(xdst + (size_t)node * 128))[sl];
  const float4 xdA = h4tof4lo(xdh);
  const float4 xdB = h4tof4hi(xdh);
  const float4 weA = *(const float4*)(Wedge + c0);
  const float4 weB = *(const float4*)(Wedge + c0 + 4);
  const float4 atA = *(const float4*)(att + c0);
  const float4 atB = *(const float4*)(att + c0 + 4);

  float m = NEG_INF, den = 0.f;
  float4 accA = {0.f, 0.f, 0.f, 0.f};
  float4 accB = {0.f, 0.f, 0.f, 0.f};

#define PREFA(kk, V, EA, HV)                               \
  {                                                        \
    const int idx = (kk) + g;                              \
    V = idx < deg;                                         \
    const int ii = V ? idx : dlast;                        \
    const unsigned rec = __shfl((int)rec_l, ii);           \
    EA = (float)(rec >> 17) * (1.f / 32767.f);             \
    const int s = rec & 0x1FFFF;                           \
    HV = ((const H8*)(xsrc + (size_t)s * 128))[sl];        \
  }

#define COMPUTE(V, EA, HV)                                         \
  {                                                                \
    const float4 VA = h4tof4lo(HV);                                \
    const float4 VB = h4tof4hi(HV);                                \
    float t, lr, p = 0.f;                                          \
    t = VA.x + xdA.x + EA * weA.x; lr = fmaxf(t, NEG_SLOPE * t); p = fmaf(lr, atA.x, p); \
    t = VA.y + xdA.y + EA * weA.y; lr = fmaxf(t, NEG_SLOPE * t); p = fmaf(lr, atA.y, p); \
    t = VA.z + xdA.z + EA * weA.z; lr = fmaxf(t, NEG_SLOPE * t); p = fmaf(lr, atA.z, p); \
    t = VA.w + xdA.w + EA * weA.w; lr = fmaxf(t, NEG_SLOPE * t); p = fmaf(lr, atA.w, p); \
    t = VB.x + xdB.x + EA * weB.x; lr = fmaxf(t, NEG_SLOPE * t); p = fmaf(lr, atB.x, p); \
    t = VB.y + xdB.y + EA * weB.y; lr = fmaxf(t, NEG_SLOPE * t); p = fmaf(lr, atB.y, p); \
    t = VB.z + xdB.z + EA * weB.z; lr = fmaxf(t, NEG_SLOPE * t); p = fmaf(lr, atB.z, p); \
    t = VB.w + xdB.w + EA * weB.w; lr = fmaxf(t, NEG_SLOPE * t); p = fmaf(lr, atB.w, p); \
    p += __shfl_xor(p, 1);                                         \
    p = V ? p : NEG_INF;                                           \
    if (p <= m) { /* common: max unchanged */                      \
      float ex = V ? __expf(p - m) : 0.f;                          \
      den += ex;                                                   \
      accA.x = fmaf(ex, VA.x, accA.x); accA.y = fmaf(ex, VA.y, accA.y); \
      accA.z = fmaf(ex, VA.z, accA.z); accA.w = fmaf(ex, VA.w, accA.w); \
      accB.x = fmaf(ex, VB.x, accB.x); accB.y = fmaf(ex, VB.y, accB.y); \
      accB.z = fmaf(ex, VB.z, accB.z); accB.w = fmaf(ex, VB.w, accB.w); \
    } else { /* new max: ex = 1 */                                 \
      const float sc = __expf(m - p);                              \
      den = fmaf(den, sc, 1.f);                                    \
      accA.x = fmaf(accA.x, sc, VA.x); accA.y = fmaf(accA.y, sc, VA.y); \
      accA.z = fmaf(accA.z, sc, VA.z); accA.w = fmaf(accA.w, sc, VA.w); \
      accB.x = fmaf(accB.x, sc, VB.x); accB.y = fmaf(accB.y, sc, VB.y); \
      accB.z = fmaf(accB.z, sc, VB.z); accB.w = fmaf(accB.w, sc, VB.w); \
      m = p;                                                       \
    }                                                              \
  }

  if (deg > 0) {
    const int dlast = deg - 1;
    bool v0, v1, v2, v3;
    float e0, e1, e2, e3;
    H8 h0, h1, h2, h3;
    PREFA(0, v0, e0, h0);
    PREFA(4, v1, e1, h1);
    PREFA(8, v2, e2, h2);
    PREFA(12, v3, e3, h3);
    for (int k = 0; k < deg; k += 4) {
      COMPUTE(v0, e0, h0);
      v0 = v1; e0 = e1; h0 = h1;
      v1 = v2; e1 = e2; h1 = h2;
      v2 = v3; e2 = e3; h2 = h3;
      PREFA(k + 16, v3, e3, h3);
    }
  }
#undef PREFA
#undef COMPUTE

  // ---- merge the 4 group states (lanes l, l^16, l^32, l^48) ----
#pragma unroll
  for (int d = 16; d < 64; d <<= 1) {
    const float mo = __shfl_xor(m, d);
    const float dno = __shfl_xor(den, d);
    const float oAx = __shfl_xor(accA.x, d), oAy = __shfl_xor(accA.y, d);
    const float oAz = __shfl_xor(accA.z, d), oAw = __shfl_xor(accA.w, d);
    const float oBx = __shfl_xor(accB.x, d), oBy = __shfl_xor(accB.y, d);
    const float oBz = __shfl_xor(accB.z, d), oBw = __shfl_xor(accB.w, d);
    const float mn = fmaxf(m, mo);
    const float sa = __expf(m - mn);
    const float sb = __expf(mo - mn);
    den = den * sa + dno * sb;
    accA.x = accA.x * sa + oAx * sb; accA.y = accA.y * sa + oAy * sb;
    accA.z = accA.z * sa + oAz * sb; accA.w = accA.w * sa + oAw * sb;
    accB.x = accB.x * sa + oBx * sb; accB.y = accB.y * sa + oBy * sb;
    accB.z = accB.z * sa + oBz * sb; accB.w = accB.w * sa + oBw * sb;
    m = mn;
  }

  const float inv = den > 0.f ? 1.f / den : 0.f;
  float o[8];
  const float4 biA = *(const float4*)(bias + c0);
  const float4 biB = *(const float4*)(bias + c0 + 4);
  o[0] = accA.x * inv + biA.x; o[1] = accA.y * inv + biA.y;
  o[2] = accA.z * inv + biA.z; o[3] = accA.w * inv + biA.w;
  o[4] = accB.x * inv + biB.x; o[5] = accB.y * inv + biB.y;
  o[6] = accB.z * inv + biB.z; o[7] = accB.w * inv + biB.w;

  // LayerNorm over 128 channels: per-lane partial over its 8, reduce over sl
  float s = 0.f;
#pragma unroll
  for (int j = 0; j < 8; ++j) s += o[j];
#pragma unroll
  for (int d = 1; d < 16; d <<= 1) s += __shfl_xor(s, d);
  const float mu = s * (1.f / 128.f);
  float q = 0.f;
#pragma unroll
  for (int j = 0; j < 8; ++j) {
    o[j] -= mu;
    q += o[j] * o[j];
  }
#pragma unroll
  for (int d = 1; d < 16; d <<= 1) q += __shfl_xor(q, d);
  const float r = rsqrtf(q * (1.f / 128.f) + 1e-5f);

  if (g == 0) {
    const float4 gaA = *(const float4*)(gamma + c0);
    const float4 gaB = *(const float4*)(gamma + c0 + 4);
    const float4 beA = *(const float4*)(beta + c0);
    const float4 beB = *(const float4*)(beta + c0 + 4);
    const float4 xrA = *(const float4*)(x + (size_t)node * 128 + c0);
    const float4 xrB = *(const float4*)(x + (size_t)node * 128 + c0 + 4);
    float ga[8] = {gaA.x, gaA.y, gaA.z, gaA.w, gaB.x, gaB.y, gaB.z, gaB.w};
    float be[8] = {beA.x, beA.y, beA.z, beA.w, beB.x, beB.y, beB.z, beB.w};
    float xr[8] = {xrA.x, xrA.y, xrA.z, xrA.w, xrB.x, xrB.y, xrB.z, xrB.w};
    float y[8];
#pragma unroll
    for (int j = 0; j < 8; ++j) {
      float v = o[j] * r * ga[j] + be[j];
      v = v > 0.f ? v : expm1f(v);
      y[j] = v + xr[j];
    }
    float4 oA = {y[0], y[1], y[2], y[3]};
    float4 oB = {y[4], y[5], y[6], y[7]};
    *(float4*)(out + (size_t)node * 128 + c0) = oA;
    *(float4*)(out + (size_t)node * 128 + c0 + 4) = oB;
  }
}

extern "C" void kernel_launch(void* const* d_in, const int* in_sizes, int n_in,
                              void* d_out, int out_size, void* d_ws, size_t ws_size,
                              hipStream_t stream) {
  const float* x = (const float*)d_in[0];
  const int* ei = (const int*)d_in[1];
  const float* eattr = (const float*)d_in[2];
  const float* Wsrc = (const float*)d_in[3];
  const float* bsrc = (const float*)d_in[4];
  const float* Wdst = (const float*)d_in[5];
  const float* bdst = (const float*)d_in[6];
  const float* Wedge = (const float*)d_in[7];
  const float* att = (const float*)d_in[8];
  const float* bias = (const float*)d_in[9];
  const float* gamma = (const float*)d_in[10];
  const float* beta = (const float*)d_in[11];
  float* out = (float*)d_out;

  // ws: xsrc fp16 25.6MB | xdst fp16 25.6MB | counts 0.4MB | buckets 25.6MB |
  //     partCount 1KB | partBuf uint2 16MB   (~94MB total)
  __half* xsrc = (__half*)d_ws;
  __half* xdst = xsrc + (size_t)NN * 128;
  int* counts = (int*)(xdst + (size_t)NN * 128);
  unsigned* buckets = (unsigned*)(counts + NN);
  int* partCount = (int*)(buckets + (size_t)NN * CAP);
  uint2* partBuf = (uint2*)(partCount + 256);

  hipMemsetAsync(partCount, 0, NPART * sizeof(int), stream);
  partition_kernel<<<dim3(P1_BLOCKS), dim3(512), 0, stream>>>(ei, eattr, partCount, partBuf);
  bucket_proj<<<dim3(NPART + PROJ_BLOCKS), dim3(512), 0, stream>>>(
      partCount, partBuf, counts, buckets, x, Wsrc, bsrc, Wdst, bdst, xsrc, xdst);
  node_kernel<<<dim3(NN / 4), dim3(256), 0, stream>>>(xsrc, xdst, counts, buckets,
                                                      Wedge, att, bias, gamma,
                                                      beta, x, out);
}